// Round 8
// baseline (258.650 us; speedup 1.0000x reference)
//
#include <hip/hip_runtime.h>

#define NROWS 8192
#define DDIM  1024           // elements per row (fp8: also bytes per row)
#define BM 128
#define BN 256
#define BKB 128              // K-bytes per tile iteration
#define NSTRIPES 8
#define CT_PER_STRIPE 4      // 8192 / (256*8)
#define MARGIN_F 0.05f
#define FP8_SCALE 8.0f       // power of 2; sims are scaled by 64 in mining space

typedef __attribute__((ext_vector_type(8)))  int   int8v;
typedef __attribute__((ext_vector_type(4)))  int   int4v;
typedef __attribute__((ext_vector_type(16))) float floatx16;

__device__ __forceinline__ void g2lds16(const void* g, void* l) {
  __builtin_amdgcn_global_load_lds(
      (const __attribute__((address_space(1))) void*)g,
      (__attribute__((address_space(3))) void*)l, 16, 0, 0);
}

// prep: 2048 blocks x 256 threads; wave w handles row 4*blockIdx + w.
// Exact fp32 pos_sim, fp32 -> fp8(e4m3, x8) quantize, zero keys + out.
__global__ void prep_kernel(const float* __restrict__ x, const float* __restrict__ y,
                            unsigned int* __restrict__ xq, unsigned int* __restrict__ yq,
                            float* __restrict__ pos, unsigned int* __restrict__ keys,
                            float* __restrict__ out) {
  const int t = threadIdx.x;
  const int lane = t & 63, wave = t >> 6;
  const int row = blockIdx.x * 4 + wave;
  const float4* xr = (const float4*)(x + (size_t)row * DDIM);
  const float4* yr = (const float4*)(y + (size_t)row * DDIM);
  unsigned int* xqr = xq + (size_t)row * 256;
  unsigned int* yqr = yq + (size_t)row * 256;
  float s = 0.f;
#pragma unroll
  for (int u = 0; u < 4; ++u) {
    const float4 a = xr[u * 64 + lane];
    const float4 b = yr[u * 64 + lane];
    s += a.x * b.x + a.y * b.y + a.z * b.z + a.w * b.w;
    int pa = __builtin_amdgcn_cvt_pk_fp8_f32(a.x * FP8_SCALE, a.y * FP8_SCALE, 0, false);
    pa     = __builtin_amdgcn_cvt_pk_fp8_f32(a.z * FP8_SCALE, a.w * FP8_SCALE, pa, true);
    int pb = __builtin_amdgcn_cvt_pk_fp8_f32(b.x * FP8_SCALE, b.y * FP8_SCALE, 0, false);
    pb     = __builtin_amdgcn_cvt_pk_fp8_f32(b.z * FP8_SCALE, b.w * FP8_SCALE, pb, true);
    xqr[u * 64 + lane] = (unsigned int)pa;
    yqr[u * 64 + lane] = (unsigned int)pb;
  }
  for (int m = 32; m; m >>= 1) s += __shfl_down(s, m, 64);
  if (lane == 0) { pos[row] = s; keys[row] = 0u; }
  if (blockIdx.x == 0 && t == 0) out[0] = 0.f;
}

// MX-fp8 32x32x64 MFMA GEMM + mask + row-argmax. 128x256 tile, 2x2 waves,
// wave = 64 rows x 128 cols (2 A-frags x 4 B-frags, 8 MFMA / 12 b128 reads).
// LDS is FRAGMENT-MAJOR: 1-KB blocks, block b holds one 64-lane b128 read-set
// (addr = const + lane*16 -> sequential, conflict-free by construction; the
// (row,chunk)->block permutation is carried by the global source address of
// global_load_lds). A block b=(wr,ks,mi,lohi); B block b=(wc,ks,ni,lohi).
// Epilogue: running 32-bit keys (monotone-f32 & ~8191 | (8191-col)) across
// the ct loop; single 32-bit butterfly + atomicMax per row per block.
__global__ __launch_bounds__(256, 2) void mine_kernel(
    const unsigned char* __restrict__ xq, const unsigned char* __restrict__ yq,
    const float* __restrict__ pos, unsigned int* __restrict__ keys) {
  __shared__ unsigned char As[BM * BKB];  // 16 KB = 16 blocks
  __shared__ unsigned char Bs[BN * BKB];  // 32 KB = 32 blocks
  __shared__ float pos_s[BM];

  const int t = threadIdx.x;
  const int rowBase = blockIdx.x * BM;
  const int stripe  = blockIdx.y;
  if (t < BM) pos_s[t] = pos[rowBase + t] * (FP8_SCALE * FP8_SCALE);

  const int lane = t & 63;
  const int wave = t >> 6;
  const int wr = wave >> 1, wc = wave & 1;
  const int r31 = lane & 31, kh = lane >> 5;

  // Read bases: frag addr = rdX + immediate(ks,mi/ni,lohi)
  const int rdA = wr * 8192  + lane * 16;
  const int rdB = wc * 16384 + lane * 16;
  // Per-lane global staging offset (bytes): row-part r31*1024, k-part kh*32
  const int goff = r31 * 1024 + kh * 32 + 16 * (wave & 1);
  // A staging: issue i -> row rowBase + 64*(i>>1) + 32*(wave>>1) + r31,
  //            k-byte k0 + 64*(i&1) + 32*kh + 16*(wave&1)
  const unsigned char* gA = xq + (size_t)(rowBase + 32 * (wave >> 1)) * 1024 + goff;

  unsigned int key[2][16];
#pragma unroll
  for (int mi = 0; mi < 2; ++mi)
#pragma unroll
    for (int reg = 0; reg < 16; ++reg) key[mi][reg] = 0u;

  for (int ct = 0; ct < CT_PER_STRIPE; ++ct) {
    const int colBase = stripe * (BN * CT_PER_STRIPE) + ct * BN;
    // B staging: issue i -> row colBase + 128*(i>>2) + 32*((wave>>1)+2*(i&1)) + r31,
    //            k-byte k0 + 64*((i>>1)&1) + 32*kh + 16*(wave&1)
    const unsigned char* gB = yq + (size_t)(colBase + 32 * (wave >> 1)) * 1024 + goff;

    floatx16 acc[2][4];
#pragma unroll
    for (int mi = 0; mi < 2; ++mi)
#pragma unroll
      for (int ni = 0; ni < 4; ++ni)
#pragma unroll
        for (int r = 0; r < 16; ++r) acc[mi][ni][r] = 0.f;

    for (int k0 = 0; k0 < DDIM; k0 += BKB) {
      __syncthreads();
#pragma unroll
      for (int i = 0; i < 4; ++i)
        g2lds16(gA + (size_t)(64 * (i >> 1)) * 1024 + k0 + 64 * (i & 1),
                &As[(i * 256 + wave * 64) * 16]);
#pragma unroll
      for (int i = 0; i < 8; ++i)
        g2lds16(gB + (size_t)(128 * (i >> 2) + 64 * (i & 1)) * 1024 + k0 + 64 * ((i >> 1) & 1),
                &Bs[(i * 256 + wave * 64) * 16]);
      __syncthreads();

#pragma unroll
      for (int ks = 0; ks < 2; ++ks) {
        int8v af[2];
#pragma unroll
        for (int mi = 0; mi < 2; ++mi) {
          int4v lo = *(const int4v*)&As[rdA + ks * 4096 + mi * 2048];
          int4v hi = *(const int4v*)&As[rdA + ks * 4096 + mi * 2048 + 1024];
          af[mi] = __builtin_shufflevector(lo, hi, 0, 1, 2, 3, 4, 5, 6, 7);
        }
#pragma unroll
        for (int ni = 0; ni < 4; ++ni) {
          int4v blo = *(const int4v*)&Bs[rdB + ks * 8192 + ni * 2048];
          int4v bhi = *(const int4v*)&Bs[rdB + ks * 8192 + ni * 2048 + 1024];
          int8v bf = __builtin_shufflevector(blo, bhi, 0, 1, 2, 3, 4, 5, 6, 7);
          acc[0][ni] = __builtin_amdgcn_mfma_scale_f32_32x32x64_f8f6f4(
              af[0], bf, acc[0][ni], 0, 0, 0, 0x7F7F7F7F, 0, 0x7F7F7F7F);
          acc[1][ni] = __builtin_amdgcn_mfma_scale_f32_32x32x64_f8f6f4(
              af[1], bf, acc[1][ni], 0, 0, 0, 0x7F7F7F7F, 0, 0x7F7F7F7F);
        }
      }
    }

    // Per-ct key update (pure VALU; no shuffles, no atomics).
    int colv[4];
#pragma unroll
    for (int ni = 0; ni < 4; ++ni) colv[ni] = colBase + 128 * wc + 32 * ni + r31;
#pragma unroll
    for (int mi = 0; mi < 2; ++mi) {
#pragma unroll
      for (int reg = 0; reg < 16; ++reg) {
        const int row_l = 64 * wr + 32 * mi + (reg & 3) + 8 * (reg >> 2) + 4 * kh;
        const int row_g = rowBase + row_l;
        const float p = pos_s[row_l];
        unsigned int kk = key[mi][reg];
#pragma unroll
        for (int ni = 0; ni < 4; ++ni) {
          const float v = acc[mi][ni][reg];
          const bool dead = (colv[ni] == row_g) || (v > p);
          unsigned int u = __float_as_uint(v);
          u ^= (unsigned int)(((int)u) >> 31) | 0x80000000u;
          unsigned int kc = (u & 0xFFFFE000u) | (unsigned int)(8191 - colv[ni]);
          kc = dead ? 0u : kc;
          kk = kk > kc ? kk : kc;
        }
        key[mi][reg] = kk;
      }
    }
  }

  // One butterfly + one atomic per owned row.
#pragma unroll
  for (int mi = 0; mi < 2; ++mi) {
#pragma unroll
    for (int reg = 0; reg < 16; ++reg) {
      unsigned int kk = key[mi][reg];
#pragma unroll
      for (int m = 1; m <= 16; m <<= 1) {
        unsigned int o = __shfl_xor(kk, m, 64);
        kk = kk > o ? kk : o;
      }
      if (r31 == 0) {
        const int row_l = 64 * wr + 32 * mi + (reg & 3) + 8 * (reg >> 2) + 4 * kh;
        atomicMax(&keys[rowBase + row_l], kk);
      }
    }
  }
}

// Exact fp32 recompute of neg_sim for the mined index + loss reduction.
__global__ void final_kernel(const float* __restrict__ x, const float* __restrict__ y,
                             const float* __restrict__ pos,
                             const unsigned int* __restrict__ keys,
                             float* __restrict__ out) {
  const int t = threadIdx.x;
  const int lane = t & 63, wave = t >> 6;
  float accl = 0.f;
#pragma unroll
  for (int i = 0; i < 8; ++i) {
    const int row = blockIdx.x * 32 + i * 4 + wave;
    const unsigned int k = keys[row];
    const int j = (k == 0u) ? 0 : (8191 - (int)(k & 8191u));  // all-masked -> argmax 0
    const float4* xr = (const float4*)(x + (size_t)row * DDIM);
    const float4* yr = (const float4*)(y + (size_t)j * DDIM);
    float s = 0.f;
#pragma unroll
    for (int u = 0; u < 4; ++u) {
      const float4 a = xr[lane + 64 * u];
      const float4 b = yr[lane + 64 * u];
      s += a.x * b.x + a.y * b.y + a.z * b.z + a.w * b.w;
    }
    for (int m = 32; m; m >>= 1) s += __shfl_down(s, m, 64);
    if (lane == 0) {
      const float l = MARGIN_F - pos[row] + s;
      accl += l > 0.f ? l : 0.f;
    }
  }
  __shared__ float ps[4];
  if (lane == 0) ps[wave] = accl;
  __syncthreads();
  if (t == 0) atomicAdd(out, (ps[0] + ps[1] + ps[2] + ps[3]) * (1.0f / (float)NROWS));
}

extern "C" void kernel_launch(void* const* d_in, const int* in_sizes, int n_in,
                              void* d_out, int out_size, void* d_ws, size_t ws_size,
                              hipStream_t stream) {
  const float* x = (const float*)d_in[0];
  const float* y = (const float*)d_in[1];
  float* out = (float*)d_out;

  // ws layout: keys 32 KB | pos 32 KB | xq 8 MB | yq 8 MB
  unsigned int* keys = (unsigned int*)d_ws;
  float* pos = (float*)((char*)d_ws + (size_t)NROWS * 4);
  unsigned char* xq = (unsigned char*)d_ws + (size_t)NROWS * 8;
  unsigned char* yq = xq + (size_t)NROWS * DDIM;

  prep_kernel<<<NROWS / 4, 256, 0, stream>>>(x, y, (unsigned int*)xq, (unsigned int*)yq,
                                             pos, keys, out);
  dim3 grid(NROWS / BM, NSTRIPES);
  mine_kernel<<<grid, 256, 0, stream>>>(xq, yq, pos, keys);
  final_kernel<<<NROWS / 32, 256, 0, stream>>>(x, y, pos, keys, out);
}

// Round 9
// 209.777 us; speedup vs baseline: 1.2330x; 1.2330x over previous
//
#include <hip/hip_runtime.h>

#define NROWS 8192
#define DDIM  1024           // elements per row (fp8: also bytes per row)
#define BM 128
#define BN 256
#define BKB 128              // K-bytes per tile iteration
#define NSTRIPES 8
#define CT_PER_STRIPE 4      // 8192 / (256*8)
#define MARGIN_F 0.05f
#define FP8_SCALE 8.0f       // power of 2; sims are scaled by 64 in mining space

typedef __attribute__((ext_vector_type(8)))  int   int8v;
typedef __attribute__((ext_vector_type(4)))  int   int4v;
typedef __attribute__((ext_vector_type(16))) float floatx16;

__device__ __forceinline__ void g2lds16(const void* g, void* l) {
  __builtin_amdgcn_global_load_lds(
      (const __attribute__((address_space(1))) void*)g,
      (__attribute__((address_space(3))) void*)l, 16, 0, 0);
}

// prep: 2048 blocks x 256 threads; wave w handles row 4*blockIdx + w.
// Exact fp32 pos_sim, fp32 -> fp8(e4m3, x8) quantize, zero keys + out.
__global__ void prep_kernel(const float* __restrict__ x, const float* __restrict__ y,
                            unsigned int* __restrict__ xq, unsigned int* __restrict__ yq,
                            float* __restrict__ pos, unsigned int* __restrict__ keys,
                            float* __restrict__ out) {
  const int t = threadIdx.x;
  const int lane = t & 63, wave = t >> 6;
  const int row = blockIdx.x * 4 + wave;
  const float4* xr = (const float4*)(x + (size_t)row * DDIM);
  const float4* yr = (const float4*)(y + (size_t)row * DDIM);
  unsigned int* xqr = xq + (size_t)row * 256;
  unsigned int* yqr = yq + (size_t)row * 256;
  float s = 0.f;
#pragma unroll
  for (int u = 0; u < 4; ++u) {
    const float4 a = xr[u * 64 + lane];
    const float4 b = yr[u * 64 + lane];
    s += a.x * b.x + a.y * b.y + a.z * b.z + a.w * b.w;
    int pa = __builtin_amdgcn_cvt_pk_fp8_f32(a.x * FP8_SCALE, a.y * FP8_SCALE, 0, false);
    pa     = __builtin_amdgcn_cvt_pk_fp8_f32(a.z * FP8_SCALE, a.w * FP8_SCALE, pa, true);
    int pb = __builtin_amdgcn_cvt_pk_fp8_f32(b.x * FP8_SCALE, b.y * FP8_SCALE, 0, false);
    pb     = __builtin_amdgcn_cvt_pk_fp8_f32(b.z * FP8_SCALE, b.w * FP8_SCALE, pb, true);
    xqr[u * 64 + lane] = (unsigned int)pa;
    yqr[u * 64 + lane] = (unsigned int)pb;
  }
  for (int m = 32; m; m >>= 1) s += __shfl_down(s, m, 64);
  if (lane == 0) { pos[row] = s; keys[row] = 0u; }
  if (blockIdx.x == 0 && t == 0) out[0] = 0.f;
}

// MX-fp8 32x32x64 MFMA GEMM + mask + row-argmax. 128x256 tile, 2x2 waves,
// wave = 64 rows x 128 cols (2 A-frags x 4 B-frags, 8 MFMA / 12 b128 reads).
// Staging: R7 scheme — coalesced row-segment global_load_lds (128-B segments
// per 8 lanes) + XOR-swizzled row-major LDS. This eats a measured 4 cyc/read
// bank-conflict tax but keeps global reads coalesced; R8's conflict-free
// fragment-major LDS scattered the GLOBAL side (16 B/lane @ 1 KB stride) and
// cost +31 us + 2.4x FETCH. Coalescing wins.
// Epilogue: R8 scheme — per-ct VALU-only running 32-bit keys
// (monotone-f32 & ~8191 | (8191-col)); single butterfly + atomicMax per row
// at kernel end (R7's per-ct 64-bit butterflies were ~20 us of LDS-permute).
__global__ __launch_bounds__(256, 2) void mine_kernel(
    const unsigned char* __restrict__ xq, const unsigned char* __restrict__ yq,
    const float* __restrict__ pos, unsigned int* __restrict__ keys) {
  __shared__ unsigned char As[BM * BKB];  // 16 KB, XOR-swizzled
  __shared__ unsigned char Bs[BN * BKB];  // 32 KB, XOR-swizzled
  __shared__ float pos_s[BM];

  const int t = threadIdx.x;
  const int rowBase = blockIdx.x * BM;
  const int stripe  = blockIdx.y;
  if (t < BM) pos_s[t] = pos[rowBase + t] * (FP8_SCALE * FP8_SCALE);

  const int lane = t & 63;
  const int wave = t >> 6;
  const int wr = wave >> 1, wc = wave & 1;
  const int r31 = lane & 31, kh = lane >> 5;
  // Swizzle: chunk c (16B) of LDS row r lives at position c^(r&7); 32|rowstep
  // so (row&7)==(r31&7) for every tile this lane touches. ks toggles byte-
  // offset bit6 (^64); the pair's second chunk toggles bit4 (^16).
  const int fragOff = ((2 * kh) ^ (r31 & 7)) << 4;
  const int offA0 = (64 * wr + r31) * BKB + fragOff;       // mi adds 32*BKB
  const int offB0 = (128 * wc + r31) * BKB + fragOff;      // ni adds 32*BKB

  unsigned int key[2][16];
#pragma unroll
  for (int mi = 0; mi < 2; ++mi)
#pragma unroll
    for (int reg = 0; reg < 16; ++reg) key[mi][reg] = 0u;

  for (int ct = 0; ct < CT_PER_STRIPE; ++ct) {
    const int colBase = stripe * (BN * CT_PER_STRIPE) + ct * BN;

    floatx16 acc[2][4];
#pragma unroll
    for (int mi = 0; mi < 2; ++mi)
#pragma unroll
      for (int ni = 0; ni < 4; ++ni)
#pragma unroll
        for (int r = 0; r < 16; ++r) acc[mi][ni][r] = 0.f;

    for (int k0 = 0; k0 < DDIM; k0 += BKB) {
      __syncthreads();  // previous iteration's ds_reads done before overwrite
      // Stage A (16 KB, 4 issues/thread) and B (32 KB, 8 issues/thread) via
      // global_load_lds width=16. 8 consecutive lanes fill one row's 128-B
      // segment -> coalesced; swizzle carried by the global source address.
#pragma unroll
      for (int i = 0; i < 4; ++i) {
        const int c  = i * 256 + t;
        const int r  = c >> 3;               // 0..127
        const int sw = (c & 7) ^ (r & 7);
        g2lds16(xq + (size_t)(rowBase + r) * DDIM + k0 + sw * 16,
                &As[(size_t)(i * 256 + wave * 64) * 16]);
      }
#pragma unroll
      for (int i = 0; i < 8; ++i) {
        const int c  = i * 256 + t;
        const int r  = c >> 3;               // 0..255
        const int sw = (c & 7) ^ (r & 7);
        g2lds16(yq + (size_t)(colBase + r) * DDIM + k0 + sw * 16,
                &Bs[(size_t)(i * 256 + wave * 64) * 16]);
      }
      __syncthreads();

#pragma unroll
      for (int ks = 0; ks < 2; ++ks) {
        const int kx = ks << 6;  // ^64 selects the second K-64 of the tile
        int8v af[2];
#pragma unroll
        for (int mi = 0; mi < 2; ++mi) {
          const int oA = (offA0 + mi * 32 * BKB) ^ kx;
          int4v lo = *(const int4v*)&As[oA];
          int4v hi = *(const int4v*)&As[oA ^ 16];
          af[mi] = __builtin_shufflevector(lo, hi, 0, 1, 2, 3, 4, 5, 6, 7);
        }
#pragma unroll
        for (int ni = 0; ni < 4; ++ni) {
          const int oB = (offB0 + ni * 32 * BKB) ^ kx;
          int4v blo = *(const int4v*)&Bs[oB];
          int4v bhi = *(const int4v*)&Bs[oB ^ 16];
          int8v bf = __builtin_shufflevector(blo, bhi, 0, 1, 2, 3, 4, 5, 6, 7);
          acc[0][ni] = __builtin_amdgcn_mfma_scale_f32_32x32x64_f8f6f4(
              af[0], bf, acc[0][ni], 0, 0, 0, 0x7F7F7F7F, 0, 0x7F7F7F7F);
          acc[1][ni] = __builtin_amdgcn_mfma_scale_f32_32x32x64_f8f6f4(
              af[1], bf, acc[1][ni], 0, 0, 0, 0x7F7F7F7F, 0, 0x7F7F7F7F);
        }
      }
    }

    // Per-ct key update (pure VALU; no shuffles, no atomics).
    // 32x32 C/D layout (HW-verified): col = lane&31,
    // row = (reg&3) + 8*(reg>>2) + 4*(lane>>5).
    int colv[4];
#pragma unroll
    for (int ni = 0; ni < 4; ++ni) colv[ni] = colBase + 128 * wc + 32 * ni + r31;
#pragma unroll
    for (int mi = 0; mi < 2; ++mi) {
#pragma unroll
      for (int reg = 0; reg < 16; ++reg) {
        const int row_l = 64 * wr + 32 * mi + (reg & 3) + 8 * (reg >> 2) + 4 * kh;
        const int row_g = rowBase + row_l;
        const float p = pos_s[row_l];
        unsigned int kk = key[mi][reg];
#pragma unroll
        for (int ni = 0; ni < 4; ++ni) {
          const float v = acc[mi][ni][reg];
          const bool dead = (colv[ni] == row_g) || (v > p);
          unsigned int u = __float_as_uint(v);
          u ^= (unsigned int)(((int)u) >> 31) | 0x80000000u;
          unsigned int kc = (u & 0xFFFFE000u) | (unsigned int)(8191 - colv[ni]);
          kc = dead ? 0u : kc;
          kk = kk > kc ? kk : kc;
        }
        key[mi][reg] = kk;
      }
    }
  }

  // One butterfly + one atomic per owned row.
#pragma unroll
  for (int mi = 0; mi < 2; ++mi) {
#pragma unroll
    for (int reg = 0; reg < 16; ++reg) {
      unsigned int kk = key[mi][reg];
#pragma unroll
      for (int m = 1; m <= 16; m <<= 1) {
        unsigned int o = __shfl_xor(kk, m, 64);
        kk = kk > o ? kk : o;
      }
      if (r31 == 0) {
        const int row_l = 64 * wr + 32 * mi + (reg & 3) + 8 * (reg >> 2) + 4 * kh;
        atomicMax(&keys[rowBase + row_l], kk);
      }
    }
  }
}

// Exact fp32 recompute of neg_sim for the mined index + loss reduction.
__global__ void final_kernel(const float* __restrict__ x, const float* __restrict__ y,
                             const float* __restrict__ pos,
                             const unsigned int* __restrict__ keys,
                             float* __restrict__ out) {
  const int t = threadIdx.x;
  const int lane = t & 63, wave = t >> 6;
  float accl = 0.f;
#pragma unroll
  for (int i = 0; i < 8; ++i) {
    const int row = blockIdx.x * 32 + i * 4 + wave;
    const unsigned int k = keys[row];
    const int j = (k == 0u) ? 0 : (8191 - (int)(k & 8191u));  // all-masked -> argmax 0
    const float4* xr = (const float4*)(x + (size_t)row * DDIM);
    const float4* yr = (const float4*)(y + (size_t)j * DDIM);
    float s = 0.f;
#pragma unroll
    for (int u = 0; u < 4; ++u) {
      const float4 a = xr[lane + 64 * u];
      const float4 b = yr[lane + 64 * u];
      s += a.x * b.x + a.y * b.y + a.z * b.z + a.w * b.w;
    }
    for (int m = 32; m; m >>= 1) s += __shfl_down(s, m, 64);
    if (lane == 0) {
      const float l = MARGIN_F - pos[row] + s;
      accl += l > 0.f ? l : 0.f;
    }
  }
  __shared__ float ps[4];
  if (lane == 0) ps[wave] = accl;
  __syncthreads();
  if (t == 0) atomicAdd(out, (ps[0] + ps[1] + ps[2] + ps[3]) * (1.0f / (float)NROWS));
}

extern "C" void kernel_launch(void* const* d_in, const int* in_sizes, int n_in,
                              void* d_out, int out_size, void* d_ws, size_t ws_size,
                              hipStream_t stream) {
  const float* x = (const float*)d_in[0];
  const float* y = (const float*)d_in[1];
  float* out = (float*)d_out;

  // ws layout: keys 32 KB | pos 32 KB | xq 8 MB | yq 8 MB
  unsigned int* keys = (unsigned int*)d_ws;
  float* pos = (float*)((char*)d_ws + (size_t)NROWS * 4);
  unsigned char* xq = (unsigned char*)d_ws + (size_t)NROWS * 8;
  unsigned char* yq = xq + (size_t)NROWS * DDIM;

  prep_kernel<<<NROWS / 4, 256, 0, stream>>>(x, y, (unsigned int*)xq, (unsigned int*)yq,
                                             pos, keys, out);
  dim3 grid(NROWS / BM, NSTRIPES);
  mine_kernel<<<grid, 256, 0, stream>>>(xq, yq, pos, keys);
  final_kernel<<<NROWS / 32, 256, 0, stream>>>(x, y, pos, keys, out);
}